// Round 11
// baseline (269.406 us; speedup 1.0000x reference)
//
#include <hip/hip_runtime.h>
#include <hip/hip_fp16.h>

#define N_NODES 100000
#define N_EDGES 1600000
#define D_IN 128
#define D_OUT 64
#define NB 391          // ceil(100000/256) buckets of 256 dst nodes
#define EPB 4096        // edges per block in bhist/part
#define NPART 391       // ceil(1600000/4096)
#define BKT_CAP 4864    // max edges per bucket (mean 4096, sigma ~64 -> 12 sigma)
#define HS_ROWS 100032  // N_NODES + 32: rows >= N_NODES are zero (DUMMY target)
#define DUMMY N_NODES   // index of a guaranteed-zero hs row

typedef _Float16 f16x8 __attribute__((ext_vector_type(8)));
typedef float f32x4 __attribute__((ext_vector_type(4)));

// ws layout (4B units):
//   counts int[N] | dinv f[N] | hs16 half[HS_ROWS*64] | part int[E] |
//   bsum int[392] | eoff int[392] | ecur int[391] | noff int[N]

// Per-block LDS bucket histogram -> few global atomics (391/block max).
__global__ __launch_bounds__(256) void k_bhist(const int* __restrict__ dst,
                                               int* __restrict__ bcnt) {
    __shared__ int lh[NB];
    const int t = threadIdx.x;
    const int e0 = blockIdx.x * EPB;
    for (int i = t; i < NB; i += 256) lh[i] = 0;
    __syncthreads();
#pragma unroll
    for (int i = 0; i < 16; i++) {
        int e = e0 + i * 256 + t;
        if (e < N_EDGES) atomicAdd(&lh[dst[e] >> 8], 1);
    }
    __syncthreads();
    for (int i = t; i < NB; i += 256) {
        int c = lh[i];
        if (c) atomicAdd(&bcnt[i], c);
    }
}

// Single block: exclusive scan of 391 bucket sums.
__global__ __launch_bounds__(512) void k_bscan(const int* __restrict__ bsum,
                                               int* __restrict__ eoff,
                                               int* __restrict__ ecur) {
    __shared__ int s[512];
    int t = threadIdx.x;
    int v = (t < NB) ? bsum[t] : 0;
    s[t] = v;
    __syncthreads();
    for (int d = 1; d < 512; d <<= 1) {
        int u = (t >= d) ? s[t - d] : 0;
        __syncthreads();
        s[t] += u;
        __syncthreads();
    }
    if (t < NB) {
        int excl = s[t] - v;
        eoff[t] = excl;
        ecur[t] = excl;
        if (t == NB - 1) eoff[NB] = s[t];
    }
}

// LDS-staged bucket partition: packed = (src<<8)|(dst&255), grouped by dst>>8.
__global__ __launch_bounds__(256) void k_part(const int* __restrict__ src,
                                              const int* __restrict__ dst,
                                              int* __restrict__ ecur,
                                              int* __restrict__ part) {
    __shared__ int lh[NB];
    __shared__ int lbase[NB + 1];
    __shared__ int ldelta[NB];
    __shared__ int lcur[NB];
    __shared__ int stage[EPB];
    __shared__ unsigned short sbk[EPB];
    const int t = threadIdx.x;
    const int e0 = blockIdx.x * EPB;
    for (int i = t; i < NB; i += 256) lh[i] = 0;
    __syncthreads();
    int p[16];
    short bk[16];
#pragma unroll
    for (int i = 0; i < 16; i++) {
        int e = e0 + i * 256 + t;
        bk[i] = -1;
        p[i] = 0;
        if (e < N_EDGES) {
            int s = src[e], d = dst[e];
            int b = d >> 8;
            bk[i] = (short)b;
            p[i] = (s << 8) | (d & 255);
            atomicAdd(&lh[b], 1);
        }
    }
    __syncthreads();
    // exclusive scan of lh[0..NB) by wave 0 (7 counters per lane)
    if (t < 64) {
        int c[7];
        int tot = 0;
#pragma unroll
        for (int j = 0; j < 7; j++) {
            int idx = t * 7 + j;
            c[j] = (idx < NB) ? lh[idx] : 0;
            tot += c[j];
        }
        int v = tot;
#pragma unroll
        for (int d = 1; d < 64; d <<= 1) {
            int u = __shfl_up(v, d);
            if (t >= d) v += u;
        }
        int run = v - tot;
#pragma unroll
        for (int j = 0; j < 7; j++) {
            int idx = t * 7 + j;
            if (idx < NB) lbase[idx] = run;
            run += c[j];
        }
        if (t == 63) lbase[NB] = run;  // total valid edges this block
    }
    __syncthreads();
    for (int i = t; i < NB; i += 256) {
        int cnt = lh[i];
        lcur[i] = lbase[i];
        if (cnt > 0) {
            int g = atomicAdd(&ecur[i], cnt);
            ldelta[i] = g - lbase[i];
        }
    }
    __syncthreads();
#pragma unroll
    for (int i = 0; i < 16; i++) {
        if (bk[i] >= 0) {
            int slot = atomicAdd(&lcur[bk[i]], 1);
            stage[slot] = p[i];
            sbk[slot] = (unsigned short)bk[i];
        }
    }
    __syncthreads();
    int nval = lbase[NB];
    for (int s = t; s < nval; s += 256) {
        part[ldelta[sbk[s]] + s] = stage[s];
    }
}

// One block per bucket: counting sort by dst low byte. Rewrites part[beg..end)
// in place as sorted src values; emits noff/counts/dinv per node (coalesced).
__global__ __launch_bounds__(256) void k_sort(const int* __restrict__ eoff,
                                              int* __restrict__ part,
                                              int* __restrict__ noff,
                                              int* __restrict__ counts,
                                              float* __restrict__ dinv) {
    __shared__ int lcnt[256], lcur[256];
    __shared__ int wsum[4];
    __shared__ int stage[BKT_CAP];
    const int t = threadIdx.x, b = blockIdx.x;
    const int beg = eoff[b], end = eoff[b + 1];
    const int m = end - beg;
    lcnt[t] = 0;
    __syncthreads();
    for (int i = t; i < m; i += 256) atomicAdd(&lcnt[part[beg + i] & 255], 1);
    __syncthreads();
    // exclusive scan of 256 counters
    int c = lcnt[t];
    int v = c;
    int lane = t & 63, w = t >> 6;
#pragma unroll
    for (int d = 1; d < 64; d <<= 1) {
        int u = __shfl_up(v, d);
        if (lane >= d) v += u;
    }
    if (lane == 63) wsum[w] = v;
    __syncthreads();
    int woff = 0;
#pragma unroll
    for (int k = 0; k < 4; k++) woff += (k < w) ? wsum[k] : 0;
    int excl = woff + v - c;
    lcur[t] = excl;
    int node = b * 256 + t;
    if (node < N_NODES) {
        noff[node] = beg + excl;
        counts[node] = c;
        dinv[node] = rsqrtf((float)c + 1.0f);
    }
    __syncthreads();
    for (int i = t; i < m; i += 256) {
        int pk = part[beg + i];
        int slot = atomicAdd(&lcur[pk & 255], 1);
        stage[slot] = pk >> 8;  // unpack src
    }
    __syncthreads();
    for (int i = t; i < m; i += 256) part[beg + i] = stage[i];
}

// MFMA f16 GEMM: 64 rows x 64 cols per block (4 waves). x,w converted to fp16
// during LDS staging, stored in MFMA fragment order. fp32 accumulate; epilogue
// scales by dinv and stores hs16. Rows N_NODES..HS_ROWS-1 are written as zero
// (DUMMY row target for k_agg padding).
__global__ __launch_bounds__(256) void k_gemm(const float* __restrict__ x,
                                              const float* __restrict__ w,
                                              const float* __restrict__ dinv,
                                              __half* __restrict__ hs16) {
    __shared__ _Float16 afr[4][4][64][8];  // [row-tile][s][lane][j] 16 KB
    __shared__ _Float16 bfr[4][4][64][8];  // [col-tile][s][lane][j] 16 KB
    const int t = threadIdx.x;
    const int row0 = blockIdx.x * 64;

    // --- stage B: w[128][64] fp32 -> fp16 frag order ---
    {
        const int col = t & 63, s = t >> 6;
        const int c = col >> 4, lb = col & 15;
#pragma unroll
        for (int g = 0; g < 4; g++) {
            union { _Float16 h[8]; uint4 u; } pk;
#pragma unroll
            for (int j = 0; j < 8; j++)
                pk.h[j] = (_Float16)w[(s * 32 + g * 8 + j) * 64 + col];
            *(uint4*)&bfr[c][s][lb | (g << 4)][0] = pk.u;
        }
    }
    // --- stage A: x rows row0..row0+63 fp32 -> fp16 frag order ---
    {
        const float4* xg = (const float4*)(x + (size_t)row0 * D_IN);
#pragma unroll
        for (int i = 0; i < 8; i++) {
            int flat = t + i * 256;        // float4 index in [64][32]
            int row = flat >> 5;
            int k4 = (flat & 31) << 2;     // k base (multiple of 4)
            float4 v = make_float4(0.f, 0.f, 0.f, 0.f);
            if (row0 + row < N_NODES) v = xg[flat];
            union { _Float16 h[4]; uint2 u; } pk;
            pk.h[0] = (_Float16)v.x; pk.h[1] = (_Float16)v.y;
            pk.h[2] = (_Float16)v.z; pk.h[3] = (_Float16)v.w;
            *(uint2*)&afr[row >> 4][k4 >> 5][(row & 15) | (((k4 >> 3) & 3) << 4)][k4 & 7] = pk.u;
        }
    }
    __syncthreads();

    const int wv = t >> 6, l = t & 63;
    f32x4 acc0 = {0.f, 0.f, 0.f, 0.f};
    f32x4 acc1 = {0.f, 0.f, 0.f, 0.f};
    f32x4 acc2 = {0.f, 0.f, 0.f, 0.f};
    f32x4 acc3 = {0.f, 0.f, 0.f, 0.f};
#pragma unroll
    for (int s = 0; s < 4; s++) {
        f16x8 a = *(const f16x8*)&afr[wv][s][l][0];
        f16x8 b0 = *(const f16x8*)&bfr[0][s][l][0];
        f16x8 b1 = *(const f16x8*)&bfr[1][s][l][0];
        f16x8 b2 = *(const f16x8*)&bfr[2][s][l][0];
        f16x8 b3 = *(const f16x8*)&bfr[3][s][l][0];
        acc0 = __builtin_amdgcn_mfma_f32_16x16x32_f16(a, b0, acc0, 0, 0, 0);
        acc1 = __builtin_amdgcn_mfma_f32_16x16x32_f16(a, b1, acc1, 0, 0, 0);
        acc2 = __builtin_amdgcn_mfma_f32_16x16x32_f16(a, b2, acc2, 0, 0, 0);
        acc3 = __builtin_amdgcn_mfma_f32_16x16x32_f16(a, b3, acc3, 0, 0, 0);
    }
    // epilogue: hs16[row][col] = fp16(acc * dinv[row]); rows >= N get dv=0 -> 0
    const int rbase = row0 + wv * 16 + ((l >> 4) << 2);
    const int cl = l & 15;
    _Float16* hsf = (_Float16*)hs16;
#pragma unroll
    for (int r = 0; r < 4; r++) {
        int row = rbase + r;  // < HS_ROWS by grid construction
        float dv = (row < N_NODES) ? dinv[row] : 0.f;
        size_t base = (size_t)row * 64 + cl;
        hsf[base +  0] = (_Float16)(acc0[r] * dv);
        hsf[base + 16] = (_Float16)(acc1[r] * dv);
        hsf[base + 32] = (_Float16)(acc2[r] * dv);
        hsf[base + 48] = (_Float16)(acc3[r] * dv);
    }
}

// One wave per node. 16-edge chunks: src indices s_loaded unconditionally and
// padded to DUMMY (zero row) via uniform cselect -> no tail code, all 8 gathers
// per lane issued in one batch. Two 32-lane halves take even/odd edges; each
// lane covers 2 cols (__half2). fp32 accumulate, shfl_xor(32) reduce, fused
// epilogue.
__global__ __launch_bounds__(256) void k_agg(const int* __restrict__ noff,
                                             const int* __restrict__ counts,
                                             const int* __restrict__ ssrc,
                                             const float* __restrict__ dinv,
                                             const __half2* __restrict__ hs2,
                                             const float* __restrict__ bias,
                                             float* __restrict__ out) {
    int t = blockIdx.x * 256 + threadIdx.x;
    int node = t >> 6, lane = t & 63;
    if (node >= N_NODES) return;
    const int half = lane >> 5;   // which edge of each pair
    const int hl = lane & 31;     // half2 column index (cols 2*hl, 2*hl+1)
    const int beg = __builtin_amdgcn_readfirstlane(noff[node]);
    const int cnt = __builtin_amdgcn_readfirstlane(counts[node]);
    float ax0 = 0.f, ay0 = 0.f, ax1 = 0.f, ay1 = 0.f;
    float ax2 = 0.f, ay2 = 0.f, ax3 = 0.f, ay3 = 0.f;
    for (int k = 0; k < cnt; k += 16) {
        int s[16];
#pragma unroll
        for (int i = 0; i < 16; i++) {
            int v = ssrc[beg + k + i];           // uniform s_load (OOB-safe in ws)
            s[i] = (k + i < cnt) ? v : DUMMY;    // uniform s_cselect padding
        }
        float2 f[8];
#pragma unroll
        for (int j = 0; j < 8; j++) {
            int r = half ? s[2 * j + 1] : s[2 * j];
            f[j] = __half22float2(hs2[((unsigned)r << 5) + hl]);
        }
        ax0 += f[0].x; ay0 += f[0].y;
        ax1 += f[1].x; ay1 += f[1].y;
        ax2 += f[2].x; ay2 += f[2].y;
        ax3 += f[3].x; ay3 += f[3].y;
        ax0 += f[4].x; ay0 += f[4].y;
        ax1 += f[5].x; ay1 += f[5].y;
        ax2 += f[6].x; ay2 += f[6].y;
        ax3 += f[7].x; ay3 += f[7].y;
    }
    float Ax = (ax0 + ax1) + (ax2 + ax3);
    float Ay = (ay0 + ay1) + (ay2 + ay3);
    Ax += __shfl_xor(Ax, 32);
    Ay += __shfl_xor(Ay, 32);
    float2 selfv = __half22float2(hs2[((unsigned)node << 5) + hl]);
    float dv = dinv[node];
    float2 bb = ((const float2*)bias)[hl];
    float vx = dv * (Ax + selfv.x) + bb.x;
    float vy = dv * (Ay + selfv.y) + bb.y;
    vx = vx > 0.f ? vx : 0.f;
    vy = vy > 0.f ? vy : 0.f;
    if (half == 0) {
        ((float2*)out)[((unsigned)node << 5) + hl] = make_float2(vx, vy);
    }
}

extern "C" void kernel_launch(void* const* d_in, const int* in_sizes, int n_in,
                              void* d_out, int out_size, void* d_ws, size_t ws_size,
                              hipStream_t stream) {
    const float* x    = (const float*)d_in[0];
    const int*   ei   = (const int*)d_in[1];   // [2][E] row-major
    const float* w    = (const float*)d_in[2];
    const float* bias = (const float*)d_in[3];
    float* out = (float*)d_out;

    int*    counts = (int*)d_ws;                         // N
    float*  dinv   = (float*)(counts + N_NODES);         // N
    __half* hs16   = (__half*)(dinv + N_NODES);          // HS_ROWS*64 halves
    int*    part   = (int*)(dinv + N_NODES) + HS_ROWS * 32;  // E
    int*    bsum   = part + N_EDGES;                     // 392
    int*    eoff   = bsum + 392;                         // NB+1
    int*    ecur   = eoff + 392;                         // NB
    int*    noff   = ecur + NB;                          // N

    const int* srcI = ei;
    const int* dstI = ei + N_EDGES;

    hipMemsetAsync(bsum, 0, NB * sizeof(int), stream);
    hipLaunchKernelGGL(k_bhist, dim3(NPART), dim3(256), 0, stream, dstI, bsum);
    hipLaunchKernelGGL(k_bscan, dim3(1), dim3(512), 0, stream, bsum, eoff, ecur);
    hipLaunchKernelGGL(k_part, dim3(NPART), dim3(256), 0, stream, srcI, dstI, ecur, part);
    hipLaunchKernelGGL(k_sort, dim3(NB), dim3(256), 0, stream, eoff, part, noff, counts, dinv);
    hipLaunchKernelGGL(k_gemm, dim3((N_NODES + 63) / 64), dim3(256), 0, stream, x, w, dinv, hs16);
    hipLaunchKernelGGL(k_agg, dim3((N_NODES * 64) / 256), dim3(256), 0, stream,
                       noff, counts, part, dinv, (const __half2*)hs16, bias, out);
}

// Round 12
// 107.139 us; speedup vs baseline: 2.5145x; 2.5145x over previous
//
#include <hip/hip_runtime.h>
#include <hip/hip_fp16.h>

#define N_NODES 100000
#define N_EDGES 1600000
#define D_IN 128
#define D_OUT 64
#define NB 391          // ceil(100000/256) buckets of 256 dst nodes
#define EPB 4096        // edges per block in bhist/part
#define NPART 391       // ceil(1600000/4096)
#define BKT_CAP 4864    // max edges per bucket (mean 4096, sigma ~64 -> 12 sigma)
#define HS_ROWS 100032  // N_NODES + 32: rows >= N_NODES are zero (DUMMY target)
#define DUMMY N_NODES   // index of a guaranteed-zero hs row

typedef _Float16 f16x8 __attribute__((ext_vector_type(8)));
typedef float f32x4 __attribute__((ext_vector_type(4)));

// ws layout (4B units):
//   counts int[N] | dinv f[N] | hs16 half[HS_ROWS*64] | part int[E] |
//   bsum int[392] | eoff int[392] | ecur int[391] | noff int[N]

// Per-block LDS bucket histogram -> few global atomics (391/block max).
__global__ __launch_bounds__(256) void k_bhist(const int* __restrict__ dst,
                                               int* __restrict__ bcnt) {
    __shared__ int lh[NB];
    const int t = threadIdx.x;
    const int e0 = blockIdx.x * EPB;
    for (int i = t; i < NB; i += 256) lh[i] = 0;
    __syncthreads();
#pragma unroll
    for (int i = 0; i < 16; i++) {
        int e = e0 + i * 256 + t;
        if (e < N_EDGES) atomicAdd(&lh[dst[e] >> 8], 1);
    }
    __syncthreads();
    for (int i = t; i < NB; i += 256) {
        int c = lh[i];
        if (c) atomicAdd(&bcnt[i], c);
    }
}

// Single block: exclusive scan of 391 bucket sums.
__global__ __launch_bounds__(512) void k_bscan(const int* __restrict__ bsum,
                                               int* __restrict__ eoff,
                                               int* __restrict__ ecur) {
    __shared__ int s[512];
    int t = threadIdx.x;
    int v = (t < NB) ? bsum[t] : 0;
    s[t] = v;
    __syncthreads();
    for (int d = 1; d < 512; d <<= 1) {
        int u = (t >= d) ? s[t - d] : 0;
        __syncthreads();
        s[t] += u;
        __syncthreads();
    }
    if (t < NB) {
        int excl = s[t] - v;
        eoff[t] = excl;
        ecur[t] = excl;
        if (t == NB - 1) eoff[NB] = s[t];
    }
}

// LDS-staged bucket partition: packed = (src<<8)|(dst&255), grouped by dst>>8.
__global__ __launch_bounds__(256) void k_part(const int* __restrict__ src,
                                              const int* __restrict__ dst,
                                              int* __restrict__ ecur,
                                              int* __restrict__ part) {
    __shared__ int lh[NB];
    __shared__ int lbase[NB + 1];
    __shared__ int ldelta[NB];
    __shared__ int lcur[NB];
    __shared__ int stage[EPB];
    __shared__ unsigned short sbk[EPB];
    const int t = threadIdx.x;
    const int e0 = blockIdx.x * EPB;
    for (int i = t; i < NB; i += 256) lh[i] = 0;
    __syncthreads();
    int p[16];
    short bk[16];
#pragma unroll
    for (int i = 0; i < 16; i++) {
        int e = e0 + i * 256 + t;
        bk[i] = -1;
        p[i] = 0;
        if (e < N_EDGES) {
            int s = src[e], d = dst[e];
            int b = d >> 8;
            bk[i] = (short)b;
            p[i] = (s << 8) | (d & 255);
            atomicAdd(&lh[b], 1);
        }
    }
    __syncthreads();
    // exclusive scan of lh[0..NB) by wave 0 (7 counters per lane)
    if (t < 64) {
        int c[7];
        int tot = 0;
#pragma unroll
        for (int j = 0; j < 7; j++) {
            int idx = t * 7 + j;
            c[j] = (idx < NB) ? lh[idx] : 0;
            tot += c[j];
        }
        int v = tot;
#pragma unroll
        for (int d = 1; d < 64; d <<= 1) {
            int u = __shfl_up(v, d);
            if (t >= d) v += u;
        }
        int run = v - tot;
#pragma unroll
        for (int j = 0; j < 7; j++) {
            int idx = t * 7 + j;
            if (idx < NB) lbase[idx] = run;
            run += c[j];
        }
        if (t == 63) lbase[NB] = run;  // total valid edges this block
    }
    __syncthreads();
    for (int i = t; i < NB; i += 256) {
        int cnt = lh[i];
        lcur[i] = lbase[i];
        if (cnt > 0) {
            int g = atomicAdd(&ecur[i], cnt);
            ldelta[i] = g - lbase[i];
        }
    }
    __syncthreads();
#pragma unroll
    for (int i = 0; i < 16; i++) {
        if (bk[i] >= 0) {
            int slot = atomicAdd(&lcur[bk[i]], 1);
            stage[slot] = p[i];
            sbk[slot] = (unsigned short)bk[i];
        }
    }
    __syncthreads();
    int nval = lbase[NB];
    for (int s = t; s < nval; s += 256) {
        part[ldelta[sbk[s]] + s] = stage[s];
    }
}

// One block per bucket: counting sort by dst low byte. Rewrites part[beg..end)
// in place as sorted src values; emits noff/counts/dinv per node (coalesced).
__global__ __launch_bounds__(256) void k_sort(const int* __restrict__ eoff,
                                              int* __restrict__ part,
                                              int* __restrict__ noff,
                                              int* __restrict__ counts,
                                              float* __restrict__ dinv) {
    __shared__ int lcnt[256], lcur[256];
    __shared__ int wsum[4];
    __shared__ int stage[BKT_CAP];
    const int t = threadIdx.x, b = blockIdx.x;
    const int beg = eoff[b], end = eoff[b + 1];
    const int m = end - beg;
    lcnt[t] = 0;
    __syncthreads();
    for (int i = t; i < m; i += 256) atomicAdd(&lcnt[part[beg + i] & 255], 1);
    __syncthreads();
    // exclusive scan of 256 counters
    int c = lcnt[t];
    int v = c;
    int lane = t & 63, w = t >> 6;
#pragma unroll
    for (int d = 1; d < 64; d <<= 1) {
        int u = __shfl_up(v, d);
        if (lane >= d) v += u;
    }
    if (lane == 63) wsum[w] = v;
    __syncthreads();
    int woff = 0;
#pragma unroll
    for (int k = 0; k < 4; k++) woff += (k < w) ? wsum[k] : 0;
    int excl = woff + v - c;
    lcur[t] = excl;
    int node = b * 256 + t;
    if (node < N_NODES) {
        noff[node] = beg + excl;
        counts[node] = c;
        dinv[node] = rsqrtf((float)c + 1.0f);
    }
    __syncthreads();
    for (int i = t; i < m; i += 256) {
        int pk = part[beg + i];
        int slot = atomicAdd(&lcur[pk & 255], 1);
        stage[slot] = pk >> 8;  // unpack src
    }
    __syncthreads();
    for (int i = t; i < m; i += 256) part[beg + i] = stage[i];
}

// MFMA f16 GEMM: 64 rows x 64 cols per block (4 waves). x,w converted to fp16
// during LDS staging, stored in MFMA fragment order. fp32 accumulate; epilogue
// scales by dinv and stores hs16. Rows N_NODES..HS_ROWS-1 are written as zero
// (DUMMY row target for k_agg padding).
__global__ __launch_bounds__(256) void k_gemm(const float* __restrict__ x,
                                              const float* __restrict__ w,
                                              const float* __restrict__ dinv,
                                              __half* __restrict__ hs16) {
    __shared__ _Float16 afr[4][4][64][8];  // [row-tile][s][lane][j] 16 KB
    __shared__ _Float16 bfr[4][4][64][8];  // [col-tile][s][lane][j] 16 KB
    const int t = threadIdx.x;
    const int row0 = blockIdx.x * 64;

    // --- stage B: w[128][64] fp32 -> fp16 frag order ---
    {
        const int col = t & 63, s = t >> 6;
        const int c = col >> 4, lb = col & 15;
#pragma unroll
        for (int g = 0; g < 4; g++) {
            union { _Float16 h[8]; uint4 u; } pk;
#pragma unroll
            for (int j = 0; j < 8; j++)
                pk.h[j] = (_Float16)w[(s * 32 + g * 8 + j) * 64 + col];
            *(uint4*)&bfr[c][s][lb | (g << 4)][0] = pk.u;
        }
    }
    // --- stage A: x rows row0..row0+63 fp32 -> fp16 frag order ---
    {
        const float4* xg = (const float4*)(x + (size_t)row0 * D_IN);
#pragma unroll
        for (int i = 0; i < 8; i++) {
            int flat = t + i * 256;        // float4 index in [64][32]
            int row = flat >> 5;
            int k4 = (flat & 31) << 2;     // k base (multiple of 4)
            float4 v = make_float4(0.f, 0.f, 0.f, 0.f);
            if (row0 + row < N_NODES) v = xg[flat];
            union { _Float16 h[4]; uint2 u; } pk;
            pk.h[0] = (_Float16)v.x; pk.h[1] = (_Float16)v.y;
            pk.h[2] = (_Float16)v.z; pk.h[3] = (_Float16)v.w;
            *(uint2*)&afr[row >> 4][k4 >> 5][(row & 15) | (((k4 >> 3) & 3) << 4)][k4 & 7] = pk.u;
        }
    }
    __syncthreads();

    const int wv = t >> 6, l = t & 63;
    f32x4 acc0 = {0.f, 0.f, 0.f, 0.f};
    f32x4 acc1 = {0.f, 0.f, 0.f, 0.f};
    f32x4 acc2 = {0.f, 0.f, 0.f, 0.f};
    f32x4 acc3 = {0.f, 0.f, 0.f, 0.f};
#pragma unroll
    for (int s = 0; s < 4; s++) {
        f16x8 a = *(const f16x8*)&afr[wv][s][l][0];
        f16x8 b0 = *(const f16x8*)&bfr[0][s][l][0];
        f16x8 b1 = *(const f16x8*)&bfr[1][s][l][0];
        f16x8 b2 = *(const f16x8*)&bfr[2][s][l][0];
        f16x8 b3 = *(const f16x8*)&bfr[3][s][l][0];
        acc0 = __builtin_amdgcn_mfma_f32_16x16x32_f16(a, b0, acc0, 0, 0, 0);
        acc1 = __builtin_amdgcn_mfma_f32_16x16x32_f16(a, b1, acc1, 0, 0, 0);
        acc2 = __builtin_amdgcn_mfma_f32_16x16x32_f16(a, b2, acc2, 0, 0, 0);
        acc3 = __builtin_amdgcn_mfma_f32_16x16x32_f16(a, b3, acc3, 0, 0, 0);
    }
    // epilogue: hs16[row][col] = fp16(acc * dinv[row]); rows >= N get dv=0 -> 0
    const int rbase = row0 + wv * 16 + ((l >> 4) << 2);
    const int cl = l & 15;
    _Float16* hsf = (_Float16*)hs16;
#pragma unroll
    for (int r = 0; r < 4; r++) {
        int row = rbase + r;  // < HS_ROWS by grid construction
        float dv = (row < N_NODES) ? dinv[row] : 0.f;
        size_t base = (size_t)row * 64 + cl;
        hsf[base +  0] = (_Float16)(acc0[r] * dv);
        hsf[base + 16] = (_Float16)(acc1[r] * dv);
        hsf[base + 32] = (_Float16)(acc2[r] * dv);
        hsf[base + 48] = (_Float16)(acc3[r] * dv);
    }
}

// One wave per node. 16-edge chunks: src indices s_loaded unconditionally into
// SIXTEEN NAMED SCALARS (no array -> nothing for PromoteAlloca to demote to
// LDS; round-11 lesson), padded to DUMMY (zero row) via uniform cselect.
// No tail code; all 8 gathers per lane issue back-to-back. Two 32-lane halves
// take even/odd edges; each lane covers 2 cols (__half2). fp32 accumulate,
// shfl_xor(32) reduce, fused epilogue.
__global__ __launch_bounds__(256) void k_agg(const int* __restrict__ noff,
                                             const int* __restrict__ counts,
                                             const int* __restrict__ ssrc,
                                             const float* __restrict__ dinv,
                                             const __half2* __restrict__ hs2,
                                             const float* __restrict__ bias,
                                             float* __restrict__ out) {
    int t = blockIdx.x * 256 + threadIdx.x;
    int node = t >> 6, lane = t & 63;
    if (node >= N_NODES) return;
    const int half = lane >> 5;   // which edge of each pair
    const int hl = lane & 31;     // half2 column index (cols 2*hl, 2*hl+1)
    const int beg = __builtin_amdgcn_readfirstlane(noff[node]);
    const int cnt = __builtin_amdgcn_readfirstlane(counts[node]);
    float ax0 = 0.f, ay0 = 0.f, ax1 = 0.f, ay1 = 0.f;
    float ax2 = 0.f, ay2 = 0.f, ax3 = 0.f, ay3 = 0.f;
    for (int k = 0; k < cnt; k += 16) {
        const int* p = ssrc + beg + k;
        int v0  = p[0],  v1  = p[1],  v2  = p[2],  v3  = p[3];
        int v4  = p[4],  v5  = p[5],  v6  = p[6],  v7  = p[7];
        int v8  = p[8],  v9  = p[9],  v10 = p[10], v11 = p[11];
        int v12 = p[12], v13 = p[13], v14 = p[14], v15 = p[15];
        int rem = cnt - k;  // uniform
        int s0  = (0  < rem) ? v0  : DUMMY;
        int s1  = (1  < rem) ? v1  : DUMMY;
        int s2  = (2  < rem) ? v2  : DUMMY;
        int s3  = (3  < rem) ? v3  : DUMMY;
        int s4  = (4  < rem) ? v4  : DUMMY;
        int s5  = (5  < rem) ? v5  : DUMMY;
        int s6  = (6  < rem) ? v6  : DUMMY;
        int s7  = (7  < rem) ? v7  : DUMMY;
        int s8  = (8  < rem) ? v8  : DUMMY;
        int s9  = (9  < rem) ? v9  : DUMMY;
        int s10 = (10 < rem) ? v10 : DUMMY;
        int s11 = (11 < rem) ? v11 : DUMMY;
        int s12 = (12 < rem) ? v12 : DUMMY;
        int s13 = (13 < rem) ? v13 : DUMMY;
        int s14 = (14 < rem) ? v14 : DUMMY;
        int s15 = (15 < rem) ? v15 : DUMMY;
        int r0 = half ? s1  : s0;
        int r1 = half ? s3  : s2;
        int r2 = half ? s5  : s4;
        int r3 = half ? s7  : s6;
        int r4 = half ? s9  : s8;
        int r5 = half ? s11 : s10;
        int r6 = half ? s13 : s12;
        int r7 = half ? s15 : s14;
        float2 f0 = __half22float2(hs2[((unsigned)r0 << 5) + hl]);
        float2 f1 = __half22float2(hs2[((unsigned)r1 << 5) + hl]);
        float2 f2 = __half22float2(hs2[((unsigned)r2 << 5) + hl]);
        float2 f3 = __half22float2(hs2[((unsigned)r3 << 5) + hl]);
        float2 f4 = __half22float2(hs2[((unsigned)r4 << 5) + hl]);
        float2 f5 = __half22float2(hs2[((unsigned)r5 << 5) + hl]);
        float2 f6 = __half22float2(hs2[((unsigned)r6 << 5) + hl]);
        float2 f7 = __half22float2(hs2[((unsigned)r7 << 5) + hl]);
        ax0 += f0.x; ay0 += f0.y;
        ax1 += f1.x; ay1 += f1.y;
        ax2 += f2.x; ay2 += f2.y;
        ax3 += f3.x; ay3 += f3.y;
        ax0 += f4.x; ay0 += f4.y;
        ax1 += f5.x; ay1 += f5.y;
        ax2 += f6.x; ay2 += f6.y;
        ax3 += f7.x; ay3 += f7.y;
    }
    float Ax = (ax0 + ax1) + (ax2 + ax3);
    float Ay = (ay0 + ay1) + (ay2 + ay3);
    Ax += __shfl_xor(Ax, 32);
    Ay += __shfl_xor(Ay, 32);
    float2 selfv = __half22float2(hs2[((unsigned)node << 5) + hl]);
    float dv = dinv[node];
    float2 bb = ((const float2*)bias)[hl];
    float vx = dv * (Ax + selfv.x) + bb.x;
    float vy = dv * (Ay + selfv.y) + bb.y;
    vx = vx > 0.f ? vx : 0.f;
    vy = vy > 0.f ? vy : 0.f;
    if (half == 0) {
        ((float2*)out)[((unsigned)node << 5) + hl] = make_float2(vx, vy);
    }
}

extern "C" void kernel_launch(void* const* d_in, const int* in_sizes, int n_in,
                              void* d_out, int out_size, void* d_ws, size_t ws_size,
                              hipStream_t stream) {
    const float* x    = (const float*)d_in[0];
    const int*   ei   = (const int*)d_in[1];   // [2][E] row-major
    const float* w    = (const float*)d_in[2];
    const float* bias = (const float*)d_in[3];
    float* out = (float*)d_out;

    int*    counts = (int*)d_ws;                         // N
    float*  dinv   = (float*)(counts + N_NODES);         // N
    __half* hs16   = (__half*)(dinv + N_NODES);          // HS_ROWS*64 halves
    int*    part   = (int*)(dinv + N_NODES) + HS_ROWS * 32;  // E
    int*    bsum   = part + N_EDGES;                     // 392
    int*    eoff   = bsum + 392;                         // NB+1
    int*    ecur   = eoff + 392;                         // NB
    int*    noff   = ecur + NB;                          // N

    const int* srcI = ei;
    const int* dstI = ei + N_EDGES;

    hipMemsetAsync(bsum, 0, NB * sizeof(int), stream);
    hipLaunchKernelGGL(k_bhist, dim3(NPART), dim3(256), 0, stream, dstI, bsum);
    hipLaunchKernelGGL(k_bscan, dim3(1), dim3(512), 0, stream, bsum, eoff, ecur);
    hipLaunchKernelGGL(k_part, dim3(NPART), dim3(256), 0, stream, srcI, dstI, ecur, part);
    hipLaunchKernelGGL(k_sort, dim3(NB), dim3(256), 0, stream, eoff, part, noff, counts, dinv);
    hipLaunchKernelGGL(k_gemm, dim3((N_NODES + 63) / 64), dim3(256), 0, stream, x, w, dinv, hs16);
    hipLaunchKernelGGL(k_agg, dim3((N_NODES * 64) / 256), dim3(256), 0, stream,
                       noff, counts, part, dinv, (const __half2*)hs16, bias, out);
}

// Round 13
// 104.973 us; speedup vs baseline: 2.5664x; 1.0206x over previous
//
#include <hip/hip_runtime.h>
#include <hip/hip_fp16.h>

#define N_NODES 100000
#define N_EDGES 1600000
#define D_IN 128
#define D_OUT 64
#define NB 391          // ceil(100000/256) buckets of 256 dst nodes
#define EPB 4096        // edges per block in bhist/part
#define NPART 391       // ceil(1600000/4096)
#define BKT_CAP 4864    // max edges per bucket (mean 4096, sigma ~64 -> 12 sigma)
#define HS_ROWS 100032  // N_NODES + 32: rows >= N_NODES are zero (DUMMY target)
#define DUMMY N_NODES   // index of a guaranteed-zero hs row

typedef _Float16 f16x8 __attribute__((ext_vector_type(8)));
typedef float f32x4 __attribute__((ext_vector_type(4)));

// ws layout (4B units):
//   counts int[N] | dinv f[N] | hs16 half[HS_ROWS*64] | part int[E] |
//   bsum int[392] | eoff int[392] | ecur int[391] | noff int[N]

// Zero the bucket counters (replaces hipMemsetAsync: a 1.5KB runtime fill was
// costing ~40us as a degenerate fillBuffer dispatch in the replay stream).
__global__ __launch_bounds__(512) void k_zero(int* __restrict__ bsum) {
    int t = threadIdx.x;
    if (t < NB) bsum[t] = 0;
}

// Per-block LDS bucket histogram -> few global atomics (391/block max).
__global__ __launch_bounds__(256) void k_bhist(const int* __restrict__ dst,
                                               int* __restrict__ bcnt) {
    __shared__ int lh[NB];
    const int t = threadIdx.x;
    const int e0 = blockIdx.x * EPB;
    for (int i = t; i < NB; i += 256) lh[i] = 0;
    __syncthreads();
#pragma unroll
    for (int i = 0; i < 16; i++) {
        int e = e0 + i * 256 + t;
        if (e < N_EDGES) atomicAdd(&lh[dst[e] >> 8], 1);
    }
    __syncthreads();
    for (int i = t; i < NB; i += 256) {
        int c = lh[i];
        if (c) atomicAdd(&bcnt[i], c);
    }
}

// Single block: exclusive scan of 391 bucket sums.
__global__ __launch_bounds__(512) void k_bscan(const int* __restrict__ bsum,
                                               int* __restrict__ eoff,
                                               int* __restrict__ ecur) {
    __shared__ int s[512];
    int t = threadIdx.x;
    int v = (t < NB) ? bsum[t] : 0;
    s[t] = v;
    __syncthreads();
    for (int d = 1; d < 512; d <<= 1) {
        int u = (t >= d) ? s[t - d] : 0;
        __syncthreads();
        s[t] += u;
        __syncthreads();
    }
    if (t < NB) {
        int excl = s[t] - v;
        eoff[t] = excl;
        ecur[t] = excl;
        if (t == NB - 1) eoff[NB] = s[t];
    }
}

// LDS-staged bucket partition: packed = (src<<8)|(dst&255), grouped by dst>>8.
__global__ __launch_bounds__(256) void k_part(const int* __restrict__ src,
                                              const int* __restrict__ dst,
                                              int* __restrict__ ecur,
                                              int* __restrict__ part) {
    __shared__ int lh[NB];
    __shared__ int lbase[NB + 1];
    __shared__ int ldelta[NB];
    __shared__ int lcur[NB];
    __shared__ int stage[EPB];
    __shared__ unsigned short sbk[EPB];
    const int t = threadIdx.x;
    const int e0 = blockIdx.x * EPB;
    for (int i = t; i < NB; i += 256) lh[i] = 0;
    __syncthreads();
    int p[16];
    short bk[16];
#pragma unroll
    for (int i = 0; i < 16; i++) {
        int e = e0 + i * 256 + t;
        bk[i] = -1;
        p[i] = 0;
        if (e < N_EDGES) {
            int s = src[e], d = dst[e];
            int b = d >> 8;
            bk[i] = (short)b;
            p[i] = (s << 8) | (d & 255);
            atomicAdd(&lh[b], 1);
        }
    }
    __syncthreads();
    // exclusive scan of lh[0..NB) by wave 0 (7 counters per lane)
    if (t < 64) {
        int c[7];
        int tot = 0;
#pragma unroll
        for (int j = 0; j < 7; j++) {
            int idx = t * 7 + j;
            c[j] = (idx < NB) ? lh[idx] : 0;
            tot += c[j];
        }
        int v = tot;
#pragma unroll
        for (int d = 1; d < 64; d <<= 1) {
            int u = __shfl_up(v, d);
            if (t >= d) v += u;
        }
        int run = v - tot;
#pragma unroll
        for (int j = 0; j < 7; j++) {
            int idx = t * 7 + j;
            if (idx < NB) lbase[idx] = run;
            run += c[j];
        }
        if (t == 63) lbase[NB] = run;  // total valid edges this block
    }
    __syncthreads();
    for (int i = t; i < NB; i += 256) {
        int cnt = lh[i];
        lcur[i] = lbase[i];
        if (cnt > 0) {
            int g = atomicAdd(&ecur[i], cnt);
            ldelta[i] = g - lbase[i];
        }
    }
    __syncthreads();
#pragma unroll
    for (int i = 0; i < 16; i++) {
        if (bk[i] >= 0) {
            int slot = atomicAdd(&lcur[bk[i]], 1);
            stage[slot] = p[i];
            sbk[slot] = (unsigned short)bk[i];
        }
    }
    __syncthreads();
    int nval = lbase[NB];
    for (int s = t; s < nval; s += 256) {
        part[ldelta[sbk[s]] + s] = stage[s];
    }
}

// One block per bucket: counting sort by dst low byte. Rewrites part[beg..end)
// in place as sorted src values; emits noff/counts/dinv per node (coalesced).
__global__ __launch_bounds__(256) void k_sort(const int* __restrict__ eoff,
                                              int* __restrict__ part,
                                              int* __restrict__ noff,
                                              int* __restrict__ counts,
                                              float* __restrict__ dinv) {
    __shared__ int lcnt[256], lcur[256];
    __shared__ int wsum[4];
    __shared__ int stage[BKT_CAP];
    const int t = threadIdx.x, b = blockIdx.x;
    const int beg = eoff[b], end = eoff[b + 1];
    const int m = end - beg;
    lcnt[t] = 0;
    __syncthreads();
    for (int i = t; i < m; i += 256) atomicAdd(&lcnt[part[beg + i] & 255], 1);
    __syncthreads();
    // exclusive scan of 256 counters
    int c = lcnt[t];
    int v = c;
    int lane = t & 63, w = t >> 6;
#pragma unroll
    for (int d = 1; d < 64; d <<= 1) {
        int u = __shfl_up(v, d);
        if (lane >= d) v += u;
    }
    if (lane == 63) wsum[w] = v;
    __syncthreads();
    int woff = 0;
#pragma unroll
    for (int k = 0; k < 4; k++) woff += (k < w) ? wsum[k] : 0;
    int excl = woff + v - c;
    lcur[t] = excl;
    int node = b * 256 + t;
    if (node < N_NODES) {
        noff[node] = beg + excl;
        counts[node] = c;
        dinv[node] = rsqrtf((float)c + 1.0f);
    }
    __syncthreads();
    for (int i = t; i < m; i += 256) {
        int pk = part[beg + i];
        int slot = atomicAdd(&lcur[pk & 255], 1);
        stage[slot] = pk >> 8;  // unpack src
    }
    __syncthreads();
    for (int i = t; i < m; i += 256) part[beg + i] = stage[i];
}

// MFMA f16 GEMM: 64 rows x 64 cols per block (4 waves). x,w converted to fp16
// during LDS staging, stored in MFMA fragment order. fp32 accumulate; epilogue
// scales by dinv and stores hs16. Rows N_NODES..HS_ROWS-1 are written as zero
// (DUMMY row target for k_agg padding).
__global__ __launch_bounds__(256) void k_gemm(const float* __restrict__ x,
                                              const float* __restrict__ w,
                                              const float* __restrict__ dinv,
                                              __half* __restrict__ hs16) {
    __shared__ _Float16 afr[4][4][64][8];  // [row-tile][s][lane][j] 16 KB
    __shared__ _Float16 bfr[4][4][64][8];  // [col-tile][s][lane][j] 16 KB
    const int t = threadIdx.x;
    const int row0 = blockIdx.x * 64;

    // --- stage B: w[128][64] fp32 -> fp16 frag order ---
    {
        const int col = t & 63, s = t >> 6;
        const int c = col >> 4, lb = col & 15;
#pragma unroll
        for (int g = 0; g < 4; g++) {
            union { _Float16 h[8]; uint4 u; } pk;
#pragma unroll
            for (int j = 0; j < 8; j++)
                pk.h[j] = (_Float16)w[(s * 32 + g * 8 + j) * 64 + col];
            *(uint4*)&bfr[c][s][lb | (g << 4)][0] = pk.u;
        }
    }
    // --- stage A: x rows row0..row0+63 fp32 -> fp16 frag order ---
    {
        const float4* xg = (const float4*)(x + (size_t)row0 * D_IN);
#pragma unroll
        for (int i = 0; i < 8; i++) {
            int flat = t + i * 256;        // float4 index in [64][32]
            int row = flat >> 5;
            int k4 = (flat & 31) << 2;     // k base (multiple of 4)
            float4 v = make_float4(0.f, 0.f, 0.f, 0.f);
            if (row0 + row < N_NODES) v = xg[flat];
            union { _Float16 h[4]; uint2 u; } pk;
            pk.h[0] = (_Float16)v.x; pk.h[1] = (_Float16)v.y;
            pk.h[2] = (_Float16)v.z; pk.h[3] = (_Float16)v.w;
            *(uint2*)&afr[row >> 4][k4 >> 5][(row & 15) | (((k4 >> 3) & 3) << 4)][k4 & 7] = pk.u;
        }
    }
    __syncthreads();

    const int wv = t >> 6, l = t & 63;
    f32x4 acc0 = {0.f, 0.f, 0.f, 0.f};
    f32x4 acc1 = {0.f, 0.f, 0.f, 0.f};
    f32x4 acc2 = {0.f, 0.f, 0.f, 0.f};
    f32x4 acc3 = {0.f, 0.f, 0.f, 0.f};
#pragma unroll
    for (int s = 0; s < 4; s++) {
        f16x8 a = *(const f16x8*)&afr[wv][s][l][0];
        f16x8 b0 = *(const f16x8*)&bfr[0][s][l][0];
        f16x8 b1 = *(const f16x8*)&bfr[1][s][l][0];
        f16x8 b2 = *(const f16x8*)&bfr[2][s][l][0];
        f16x8 b3 = *(const f16x8*)&bfr[3][s][l][0];
        acc0 = __builtin_amdgcn_mfma_f32_16x16x32_f16(a, b0, acc0, 0, 0, 0);
        acc1 = __builtin_amdgcn_mfma_f32_16x16x32_f16(a, b1, acc1, 0, 0, 0);
        acc2 = __builtin_amdgcn_mfma_f32_16x16x32_f16(a, b2, acc2, 0, 0, 0);
        acc3 = __builtin_amdgcn_mfma_f32_16x16x32_f16(a, b3, acc3, 0, 0, 0);
    }
    // epilogue: hs16[row][col] = fp16(acc * dinv[row]); rows >= N get dv=0 -> 0
    const int rbase = row0 + wv * 16 + ((l >> 4) << 2);
    const int cl = l & 15;
    _Float16* hsf = (_Float16*)hs16;
#pragma unroll
    for (int r = 0; r < 4; r++) {
        int row = rbase + r;  // < HS_ROWS by grid construction
        float dv = (row < N_NODES) ? dinv[row] : 0.f;
        size_t base = (size_t)row * 64 + cl;
        hsf[base +  0] = (_Float16)(acc0[r] * dv);
        hsf[base + 16] = (_Float16)(acc1[r] * dv);
        hsf[base + 32] = (_Float16)(acc2[r] * dv);
        hsf[base + 48] = (_Float16)(acc3[r] * dv);
    }
}

// One wave per node. 16-edge chunks: src indices s_loaded unconditionally into
// sixteen named scalars (no array -> no PromoteAlloca LDS demotion), padded to
// DUMMY (zero row) via uniform cselect. No tail code; all 8 gathers per lane
// issue back-to-back. Two 32-lane halves take even/odd edges; each lane covers
// 2 cols (__half2). fp32 accumulate, shfl_xor(32) reduce, fused epilogue.
__global__ __launch_bounds__(256) void k_agg(const int* __restrict__ noff,
                                             const int* __restrict__ counts,
                                             const int* __restrict__ ssrc,
                                             const float* __restrict__ dinv,
                                             const __half2* __restrict__ hs2,
                                             const float* __restrict__ bias,
                                             float* __restrict__ out) {
    int t = blockIdx.x * 256 + threadIdx.x;
    int node = t >> 6, lane = t & 63;
    if (node >= N_NODES) return;
    const int half = lane >> 5;   // which edge of each pair
    const int hl = lane & 31;     // half2 column index (cols 2*hl, 2*hl+1)
    const int beg = __builtin_amdgcn_readfirstlane(noff[node]);
    const int cnt = __builtin_amdgcn_readfirstlane(counts[node]);
    float ax0 = 0.f, ay0 = 0.f, ax1 = 0.f, ay1 = 0.f;
    float ax2 = 0.f, ay2 = 0.f, ax3 = 0.f, ay3 = 0.f;
    for (int k = 0; k < cnt; k += 16) {
        const int* p = ssrc + beg + k;
        int v0  = p[0],  v1  = p[1],  v2  = p[2],  v3  = p[3];
        int v4  = p[4],  v5  = p[5],  v6  = p[6],  v7  = p[7];
        int v8  = p[8],  v9  = p[9],  v10 = p[10], v11 = p[11];
        int v12 = p[12], v13 = p[13], v14 = p[14], v15 = p[15];
        int rem = cnt - k;  // uniform
        int s0  = (0  < rem) ? v0  : DUMMY;
        int s1  = (1  < rem) ? v1  : DUMMY;
        int s2  = (2  < rem) ? v2  : DUMMY;
        int s3  = (3  < rem) ? v3  : DUMMY;
        int s4  = (4  < rem) ? v4  : DUMMY;
        int s5  = (5  < rem) ? v5  : DUMMY;
        int s6  = (6  < rem) ? v6  : DUMMY;
        int s7  = (7  < rem) ? v7  : DUMMY;
        int s8  = (8  < rem) ? v8  : DUMMY;
        int s9  = (9  < rem) ? v9  : DUMMY;
        int s10 = (10 < rem) ? v10 : DUMMY;
        int s11 = (11 < rem) ? v11 : DUMMY;
        int s12 = (12 < rem) ? v12 : DUMMY;
        int s13 = (13 < rem) ? v13 : DUMMY;
        int s14 = (14 < rem) ? v14 : DUMMY;
        int s15 = (15 < rem) ? v15 : DUMMY;
        int r0 = half ? s1  : s0;
        int r1 = half ? s3  : s2;
        int r2 = half ? s5  : s4;
        int r3 = half ? s7  : s6;
        int r4 = half ? s9  : s8;
        int r5 = half ? s11 : s10;
        int r6 = half ? s13 : s12;
        int r7 = half ? s15 : s14;
        float2 f0 = __half22float2(hs2[((unsigned)r0 << 5) + hl]);
        float2 f1 = __half22float2(hs2[((unsigned)r1 << 5) + hl]);
        float2 f2 = __half22float2(hs2[((unsigned)r2 << 5) + hl]);
        float2 f3 = __half22float2(hs2[((unsigned)r3 << 5) + hl]);
        float2 f4 = __half22float2(hs2[((unsigned)r4 << 5) + hl]);
        float2 f5 = __half22float2(hs2[((unsigned)r5 << 5) + hl]);
        float2 f6 = __half22float2(hs2[((unsigned)r6 << 5) + hl]);
        float2 f7 = __half22float2(hs2[((unsigned)r7 << 5) + hl]);
        ax0 += f0.x; ay0 += f0.y;
        ax1 += f1.x; ay1 += f1.y;
        ax2 += f2.x; ay2 += f2.y;
        ax3 += f3.x; ay3 += f3.y;
        ax0 += f4.x; ay0 += f4.y;
        ax1 += f5.x; ay1 += f5.y;
        ax2 += f6.x; ay2 += f6.y;
        ax3 += f7.x; ay3 += f7.y;
    }
    float Ax = (ax0 + ax1) + (ax2 + ax3);
    float Ay = (ay0 + ay1) + (ay2 + ay3);
    Ax += __shfl_xor(Ax, 32);
    Ay += __shfl_xor(Ay, 32);
    float2 selfv = __half22float2(hs2[((unsigned)node << 5) + hl]);
    float dv = dinv[node];
    float2 bb = ((const float2*)bias)[hl];
    float vx = dv * (Ax + selfv.x) + bb.x;
    float vy = dv * (Ay + selfv.y) + bb.y;
    vx = vx > 0.f ? vx : 0.f;
    vy = vy > 0.f ? vy : 0.f;
    if (half == 0) {
        ((float2*)out)[((unsigned)node << 5) + hl] = make_float2(vx, vy);
    }
}

extern "C" void kernel_launch(void* const* d_in, const int* in_sizes, int n_in,
                              void* d_out, int out_size, void* d_ws, size_t ws_size,
                              hipStream_t stream) {
    const float* x    = (const float*)d_in[0];
    const int*   ei   = (const int*)d_in[1];   // [2][E] row-major
    const float* w    = (const float*)d_in[2];
    const float* bias = (const float*)d_in[3];
    float* out = (float*)d_out;

    int*    counts = (int*)d_ws;                         // N
    float*  dinv   = (float*)(counts + N_NODES);         // N
    __half* hs16   = (__half*)(dinv + N_NODES);          // HS_ROWS*64 halves
    int*    part   = (int*)(dinv + N_NODES) + HS_ROWS * 32;  // E
    int*    bsum   = part + N_EDGES;                     // 392
    int*    eoff   = bsum + 392;                         // NB+1
    int*    ecur   = eoff + 392;                         // NB
    int*    noff   = ecur + NB;                          // N

    const int* srcI = ei;
    const int* dstI = ei + N_EDGES;

    hipLaunchKernelGGL(k_zero, dim3(1), dim3(512), 0, stream, bsum);
    hipLaunchKernelGGL(k_bhist, dim3(NPART), dim3(256), 0, stream, dstI, bsum);
    hipLaunchKernelGGL(k_bscan, dim3(1), dim3(512), 0, stream, bsum, eoff, ecur);
    hipLaunchKernelGGL(k_part, dim3(NPART), dim3(256), 0, stream, srcI, dstI, ecur, part);
    hipLaunchKernelGGL(k_sort, dim3(NB), dim3(256), 0, stream, eoff, part, noff, counts, dinv);
    hipLaunchKernelGGL(k_gemm, dim3((N_NODES + 63) / 64), dim3(256), 0, stream, x, w, dinv, hs16);
    hipLaunchKernelGGL(k_agg, dim3((N_NODES * 64) / 256), dim3(256), 0, stream,
                       noff, counts, part, dinv, (const __half2*)hs16, bias, out);
}

// Round 14
// 76.446 us; speedup vs baseline: 3.5241x; 1.3732x over previous
//
#include <hip/hip_runtime.h>
#include <hip/hip_fp16.h>

#define N_NODES 100000
#define N_EDGES 1600000
#define D_IN 128
#define D_OUT 64
#define NB 391          // ceil(100000/256) buckets of 256 dst nodes
#define EPB 4096        // edges per partition block
#define NPART 391       // ceil(1600000/4096) partition blocks
#define BKT_CAP 4864    // max edges per bucket (mean 4096, sigma ~64 -> 12 sigma)
#define HS_ROWS 100032  // N_NODES + 32: rows >= N_NODES are zero (DUMMY target)
#define DUMMY N_NODES   // index of a guaranteed-zero hs row

typedef _Float16 f16x8 __attribute__((ext_vector_type(8)));
typedef float f32x4 __attribute__((ext_vector_type(4)));

// ws layout (4B units):
//   counts int[N] | dinv f[N] | hs16 half[HS_ROWS*64] | part1 int[E] |
//   dir int[NPART*(NB+1)] | part2 int[NB*BKT_CAP+16] | noff int[N]

// Block-local bucket partition, NO global atomics/scans: block b groups its
// 4096 edges by dst bucket into part1[b*EPB..], writes per-block directory
// dir[b][0..NB] (exclusive offsets + total). packed = (src<<8)|(dst&255).
__global__ __launch_bounds__(512) void k_part(const int* __restrict__ src,
                                              const int* __restrict__ dst,
                                              int* __restrict__ part1,
                                              int* __restrict__ dir) {
    __shared__ int lh[NB];
    __shared__ int lbase[NB + 1];
    __shared__ int lcur[NB];
    __shared__ int stage[EPB];
    const int t = threadIdx.x;
    const int e0 = blockIdx.x * EPB;
    for (int i = t; i < NB; i += 512) lh[i] = 0;
    __syncthreads();
    int p[8];
    short bk[8];
#pragma unroll
    for (int i = 0; i < 8; i++) {
        int e = e0 + i * 512 + t;
        bk[i] = -1;
        p[i] = 0;
        if (e < N_EDGES) {
            int s = src[e], d = dst[e];
            int b = d >> 8;
            bk[i] = (short)b;
            p[i] = (s << 8) | (d & 255);
            atomicAdd(&lh[b], 1);
        }
    }
    __syncthreads();
    // exclusive scan of lh[0..NB) by wave 0 (7 counters per lane)
    if (t < 64) {
        int c[7];
        int tot = 0;
#pragma unroll
        for (int j = 0; j < 7; j++) {
            int idx = t * 7 + j;
            c[j] = (idx < NB) ? lh[idx] : 0;
            tot += c[j];
        }
        int v = tot;
#pragma unroll
        for (int d = 1; d < 64; d <<= 1) {
            int u = __shfl_up(v, d);
            if (t >= d) v += u;
        }
        int run = v - tot;
#pragma unroll
        for (int j = 0; j < 7; j++) {
            int idx = t * 7 + j;
            if (idx < NB) lbase[idx] = run;
            run += c[j];
        }
        if (t == 63) lbase[NB] = run;  // total valid edges this block
    }
    __syncthreads();
    for (int i = t; i < NB; i += 512) lcur[i] = lbase[i];
    __syncthreads();
#pragma unroll
    for (int i = 0; i < 8; i++) {
        if (bk[i] >= 0) {
            int slot = atomicAdd(&lcur[bk[i]], 1);
            stage[slot] = p[i];
        }
    }
    __syncthreads();
    const int nval = lbase[NB];
    for (int s = t; s < nval; s += 512) part1[e0 + s] = stage[s];
    int* dblk = dir + blockIdx.x * (NB + 1);
    for (int i = t; i <= NB; i += 512) dblk[i] = lbase[i];
}

// One block per bucket (512 thr): gather this bucket's runs from all NPART
// block segments via dir, counting-sort by dst low byte in LDS, write sorted
// src to part2[bucket*BKT_CAP..] (fixed stride -> no global scan), emit
// noff/counts/dinv per node (coalesced).
__global__ __launch_bounds__(512) void k_sort(const int* __restrict__ part1,
                                              const int* __restrict__ dir,
                                              int* __restrict__ part2,
                                              int* __restrict__ noff,
                                              int* __restrict__ counts,
                                              float* __restrict__ dinv) {
    __shared__ int sbeg[NPART], slen[NPART], spref[NPART];
    __shared__ int lcnt[256], lcur[256];
    __shared__ int wsum[4];
    __shared__ int stage[BKT_CAP];
    __shared__ int stage2[BKT_CAP];
    __shared__ int mtot;
    const int t = threadIdx.x, b = blockIdx.x;  // b = bucket
    for (int r = t; r < NPART; r += 512) {
        const int* dblk = dir + r * (NB + 1);
        int s0 = dblk[b];
        sbeg[r] = s0;
        slen[r] = dblk[b + 1] - s0;
    }
    if (t < 256) lcnt[t] = 0;
    __syncthreads();
    // exclusive scan of slen[0..NPART) by wave 0
    if (t < 64) {
        int c[7];
        int tot = 0;
#pragma unroll
        for (int j = 0; j < 7; j++) {
            int idx = t * 7 + j;
            c[j] = (idx < NPART) ? slen[idx] : 0;
            tot += c[j];
        }
        int v = tot;
#pragma unroll
        for (int d = 1; d < 64; d <<= 1) {
            int u = __shfl_up(v, d);
            if (t >= d) v += u;
        }
        int run = v - tot;
#pragma unroll
        for (int j = 0; j < 7; j++) {
            int idx = t * 7 + j;
            if (idx < NPART) spref[idx] = run;
            run += c[j];
        }
        if (t == 63) mtot = run;
    }
    __syncthreads();
    const int m = mtot;  // edges in this bucket
    // gather runs into contiguous LDS stage
    for (int r = t; r < NPART; r += 512) {
        const int* sp = part1 + r * EPB + sbeg[r];
        int o = spref[r], L = slen[r];
        for (int j = 0; j < L; j++) stage[o + j] = sp[j];
    }
    __syncthreads();
    // histogram by dst low byte
    for (int s = t; s < m; s += 512) atomicAdd(&lcnt[stage[s] & 255], 1);
    __syncthreads();
    // exclusive scan of 256 counters (waves 0-3)
    int c = 0, v = 0;
    const int lane = t & 63, w = t >> 6;
    if (t < 256) {
        c = lcnt[t];
        v = c;
#pragma unroll
        for (int d = 1; d < 64; d <<= 1) {
            int u = __shfl_up(v, d);
            if (lane >= d) v += u;
        }
        if (lane == 63) wsum[w] = v;
    }
    __syncthreads();
    if (t < 256) {
        int woff = 0;
#pragma unroll
        for (int k = 0; k < 4; k++) woff += (k < w) ? wsum[k] : 0;
        int excl = woff + v - c;
        lcur[t] = excl;
        int node = b * 256 + t;
        if (node < N_NODES) {
            noff[node] = b * BKT_CAP + excl;
            counts[node] = c;
            dinv[node] = rsqrtf((float)c + 1.0f);
        }
    }
    __syncthreads();
    for (int s = t; s < m; s += 512) {
        int pk = stage[s];
        int slot = atomicAdd(&lcur[pk & 255], 1);
        stage2[slot] = pk >> 8;  // unpack src
    }
    __syncthreads();
    int* outp = part2 + b * BKT_CAP;
    for (int s = t; s < m; s += 512) outp[s] = stage2[s];
}

// MFMA f16 GEMM: 64 rows x 64 cols per block (4 waves). x,w converted to fp16
// during LDS staging, stored in MFMA fragment order. fp32 accumulate; epilogue
// scales by dinv and stores hs16. Rows N_NODES..HS_ROWS-1 are written as zero
// (DUMMY row target for k_agg padding).
__global__ __launch_bounds__(256) void k_gemm(const float* __restrict__ x,
                                              const float* __restrict__ w,
                                              const float* __restrict__ dinv,
                                              __half* __restrict__ hs16) {
    __shared__ _Float16 afr[4][4][64][8];  // [row-tile][s][lane][j] 16 KB
    __shared__ _Float16 bfr[4][4][64][8];  // [col-tile][s][lane][j] 16 KB
    const int t = threadIdx.x;
    const int row0 = blockIdx.x * 64;

    // --- stage B: w[128][64] fp32 -> fp16 frag order ---
    {
        const int col = t & 63, s = t >> 6;
        const int c = col >> 4, lb = col & 15;
#pragma unroll
        for (int g = 0; g < 4; g++) {
            union { _Float16 h[8]; uint4 u; } pk;
#pragma unroll
            for (int j = 0; j < 8; j++)
                pk.h[j] = (_Float16)w[(s * 32 + g * 8 + j) * 64 + col];
            *(uint4*)&bfr[c][s][lb | (g << 4)][0] = pk.u;
        }
    }
    // --- stage A: x rows row0..row0+63 fp32 -> fp16 frag order ---
    {
        const float4* xg = (const float4*)(x + (size_t)row0 * D_IN);
#pragma unroll
        for (int i = 0; i < 8; i++) {
            int flat = t + i * 256;        // float4 index in [64][32]
            int row = flat >> 5;
            int k4 = (flat & 31) << 2;     // k base (multiple of 4)
            float4 v = make_float4(0.f, 0.f, 0.f, 0.f);
            if (row0 + row < N_NODES) v = xg[flat];
            union { _Float16 h[4]; uint2 u; } pk;
            pk.h[0] = (_Float16)v.x; pk.h[1] = (_Float16)v.y;
            pk.h[2] = (_Float16)v.z; pk.h[3] = (_Float16)v.w;
            *(uint2*)&afr[row >> 4][k4 >> 5][(row & 15) | (((k4 >> 3) & 3) << 4)][k4 & 7] = pk.u;
        }
    }
    __syncthreads();

    const int wv = t >> 6, l = t & 63;
    f32x4 acc0 = {0.f, 0.f, 0.f, 0.f};
    f32x4 acc1 = {0.f, 0.f, 0.f, 0.f};
    f32x4 acc2 = {0.f, 0.f, 0.f, 0.f};
    f32x4 acc3 = {0.f, 0.f, 0.f, 0.f};
#pragma unroll
    for (int s = 0; s < 4; s++) {
        f16x8 a = *(const f16x8*)&afr[wv][s][l][0];
        f16x8 b0 = *(const f16x8*)&bfr[0][s][l][0];
        f16x8 b1 = *(const f16x8*)&bfr[1][s][l][0];
        f16x8 b2 = *(const f16x8*)&bfr[2][s][l][0];
        f16x8 b3 = *(const f16x8*)&bfr[3][s][l][0];
        acc0 = __builtin_amdgcn_mfma_f32_16x16x32_f16(a, b0, acc0, 0, 0, 0);
        acc1 = __builtin_amdgcn_mfma_f32_16x16x32_f16(a, b1, acc1, 0, 0, 0);
        acc2 = __builtin_amdgcn_mfma_f32_16x16x32_f16(a, b2, acc2, 0, 0, 0);
        acc3 = __builtin_amdgcn_mfma_f32_16x16x32_f16(a, b3, acc3, 0, 0, 0);
    }
    // epilogue: hs16[row][col] = fp16(acc * dinv[row]); rows >= N get dv=0 -> 0
    const int rbase = row0 + wv * 16 + ((l >> 4) << 2);
    const int cl = l & 15;
    _Float16* hsf = (_Float16*)hs16;
#pragma unroll
    for (int r = 0; r < 4; r++) {
        int row = rbase + r;  // < HS_ROWS by grid construction
        float dv = (row < N_NODES) ? dinv[row] : 0.f;
        size_t base = (size_t)row * 64 + cl;
        hsf[base +  0] = (_Float16)(acc0[r] * dv);
        hsf[base + 16] = (_Float16)(acc1[r] * dv);
        hsf[base + 32] = (_Float16)(acc2[r] * dv);
        hsf[base + 48] = (_Float16)(acc3[r] * dv);
    }
}

// One wave per node. 16-edge chunks: src indices s_loaded unconditionally into
// sixteen named scalars (no array -> no PromoteAlloca LDS demotion), padded to
// DUMMY (zero row) via uniform cselect. No tail code; all 8 gathers per lane
// issue back-to-back. Two 32-lane halves take even/odd edges; each lane covers
// 2 cols (__half2). fp32 accumulate, shfl_xor(32) reduce, fused epilogue.
__global__ __launch_bounds__(256) void k_agg(const int* __restrict__ noff,
                                             const int* __restrict__ counts,
                                             const int* __restrict__ ssrc,
                                             const float* __restrict__ dinv,
                                             const __half2* __restrict__ hs2,
                                             const float* __restrict__ bias,
                                             float* __restrict__ out) {
    int t = blockIdx.x * 256 + threadIdx.x;
    int node = t >> 6, lane = t & 63;
    if (node >= N_NODES) return;
    const int half = lane >> 5;   // which edge of each pair
    const int hl = lane & 31;     // half2 column index (cols 2*hl, 2*hl+1)
    const int beg = __builtin_amdgcn_readfirstlane(noff[node]);
    const int cnt = __builtin_amdgcn_readfirstlane(counts[node]);
    float ax0 = 0.f, ay0 = 0.f, ax1 = 0.f, ay1 = 0.f;
    float ax2 = 0.f, ay2 = 0.f, ax3 = 0.f, ay3 = 0.f;
    for (int k = 0; k < cnt; k += 16) {
        const int* p = ssrc + beg + k;
        int v0  = p[0],  v1  = p[1],  v2  = p[2],  v3  = p[3];
        int v4  = p[4],  v5  = p[5],  v6  = p[6],  v7  = p[7];
        int v8  = p[8],  v9  = p[9],  v10 = p[10], v11 = p[11];
        int v12 = p[12], v13 = p[13], v14 = p[14], v15 = p[15];
        int rem = cnt - k;  // uniform
        int s0  = (0  < rem) ? v0  : DUMMY;
        int s1  = (1  < rem) ? v1  : DUMMY;
        int s2  = (2  < rem) ? v2  : DUMMY;
        int s3  = (3  < rem) ? v3  : DUMMY;
        int s4  = (4  < rem) ? v4  : DUMMY;
        int s5  = (5  < rem) ? v5  : DUMMY;
        int s6  = (6  < rem) ? v6  : DUMMY;
        int s7  = (7  < rem) ? v7  : DUMMY;
        int s8  = (8  < rem) ? v8  : DUMMY;
        int s9  = (9  < rem) ? v9  : DUMMY;
        int s10 = (10 < rem) ? v10 : DUMMY;
        int s11 = (11 < rem) ? v11 : DUMMY;
        int s12 = (12 < rem) ? v12 : DUMMY;
        int s13 = (13 < rem) ? v13 : DUMMY;
        int s14 = (14 < rem) ? v14 : DUMMY;
        int s15 = (15 < rem) ? v15 : DUMMY;
        int r0 = half ? s1  : s0;
        int r1 = half ? s3  : s2;
        int r2 = half ? s5  : s4;
        int r3 = half ? s7  : s6;
        int r4 = half ? s9  : s8;
        int r5 = half ? s11 : s10;
        int r6 = half ? s13 : s12;
        int r7 = half ? s15 : s14;
        float2 f0 = __half22float2(hs2[((unsigned)r0 << 5) + hl]);
        float2 f1 = __half22float2(hs2[((unsigned)r1 << 5) + hl]);
        float2 f2 = __half22float2(hs2[((unsigned)r2 << 5) + hl]);
        float2 f3 = __half22float2(hs2[((unsigned)r3 << 5) + hl]);
        float2 f4 = __half22float2(hs2[((unsigned)r4 << 5) + hl]);
        float2 f5 = __half22float2(hs2[((unsigned)r5 << 5) + hl]);
        float2 f6 = __half22float2(hs2[((unsigned)r6 << 5) + hl]);
        float2 f7 = __half22float2(hs2[((unsigned)r7 << 5) + hl]);
        ax0 += f0.x; ay0 += f0.y;
        ax1 += f1.x; ay1 += f1.y;
        ax2 += f2.x; ay2 += f2.y;
        ax3 += f3.x; ay3 += f3.y;
        ax0 += f4.x; ay0 += f4.y;
        ax1 += f5.x; ay1 += f5.y;
        ax2 += f6.x; ay2 += f6.y;
        ax3 += f7.x; ay3 += f7.y;
    }
    float Ax = (ax0 + ax1) + (ax2 + ax3);
    float Ay = (ay0 + ay1) + (ay2 + ay3);
    Ax += __shfl_xor(Ax, 32);
    Ay += __shfl_xor(Ay, 32);
    float2 selfv = __half22float2(hs2[((unsigned)node << 5) + hl]);
    float dv = dinv[node];
    float2 bb = ((const float2*)bias)[hl];
    float vx = dv * (Ax + selfv.x) + bb.x;
    float vy = dv * (Ay + selfv.y) + bb.y;
    vx = vx > 0.f ? vx : 0.f;
    vy = vy > 0.f ? vy : 0.f;
    if (half == 0) {
        ((float2*)out)[((unsigned)node << 5) + hl] = make_float2(vx, vy);
    }
}

extern "C" void kernel_launch(void* const* d_in, const int* in_sizes, int n_in,
                              void* d_out, int out_size, void* d_ws, size_t ws_size,
                              hipStream_t stream) {
    const float* x    = (const float*)d_in[0];
    const int*   ei   = (const int*)d_in[1];   // [2][E] row-major
    const float* w    = (const float*)d_in[2];
    const float* bias = (const float*)d_in[3];
    float* out = (float*)d_out;

    int*    counts = (int*)d_ws;                         // N
    float*  dinv   = (float*)(counts + N_NODES);         // N
    __half* hs16   = (__half*)(dinv + N_NODES);          // HS_ROWS*64 halves
    int*    part1  = (int*)(dinv + N_NODES) + HS_ROWS * 32;  // E
    int*    dir    = part1 + N_EDGES;                    // NPART*(NB+1)
    int*    part2  = dir + NPART * (NB + 1);             // NB*BKT_CAP+16
    int*    noff   = part2 + NB * BKT_CAP + 16;          // N

    const int* srcI = ei;
    const int* dstI = ei + N_EDGES;

    hipLaunchKernelGGL(k_part, dim3(NPART), dim3(512), 0, stream, srcI, dstI, part1, dir);
    hipLaunchKernelGGL(k_sort, dim3(NB), dim3(512), 0, stream, part1, dir, part2, noff, counts, dinv);
    hipLaunchKernelGGL(k_gemm, dim3((N_NODES + 63) / 64), dim3(256), 0, stream, x, w, dinv, hs16);
    hipLaunchKernelGGL(k_agg, dim3((N_NODES * 64) / 256), dim3(256), 0, stream,
                       noff, counts, part2, dinv, (const __half2*)hs16, bias, out);
}

// Round 15
// 74.584 us; speedup vs baseline: 3.6121x; 1.0250x over previous
//
#include <hip/hip_runtime.h>
#include <hip/hip_fp16.h>

#define N_NODES 100000
#define N_EDGES 1600000
#define D_IN 128
#define D_OUT 64
#define NB 391          // ceil(100000/256) buckets of 256 dst nodes
#define EPB 4096        // edges per partition block
#define NPART 391       // ceil(1600000/4096) partition blocks
#define BKT_CAP 4864    // max edges per bucket (mean 4092, sigma ~64 -> 12 sigma)
#define HS_ROWS 100032  // N_NODES + 32: rows >= N_NODES are zero (DUMMY target)
#define DUMMY N_NODES   // index of a guaranteed-zero hs row

typedef _Float16 f16x8 __attribute__((ext_vector_type(8)));
typedef float f32x4 __attribute__((ext_vector_type(4)));

// ws layout (4B units):
//   dinv f[N] | hs16 half[HS_ROWS*64] | part1 int[E] |
//   dir int[NPART*(NB+1)] | part2 int[NB*BKT_CAP+16] | nfo int2[N]

// Block-local bucket partition, NO global atomics/scans: block b groups its
// 4096 edges by dst bucket into part1[b*EPB..], writes per-block directory
// dir[b][0..NB] (exclusive offsets + total). packed = (src<<8)|(dst&255).
__global__ __launch_bounds__(512) void k_part(const int* __restrict__ src,
                                              const int* __restrict__ dst,
                                              int* __restrict__ part1,
                                              int* __restrict__ dir) {
    __shared__ int lh[NB];
    __shared__ int lbase[NB + 1];
    __shared__ int lcur[NB];
    __shared__ alignas(16) int stage[EPB];
    const int t = threadIdx.x;
    const int e0 = blockIdx.x * EPB;
    for (int i = t; i < NB; i += 512) lh[i] = 0;
    __syncthreads();
    int p[8];
    short bk[8];
#pragma unroll
    for (int i = 0; i < 8; i++) {
        int e = e0 + i * 512 + t;
        bk[i] = -1;
        p[i] = 0;
        if (e < N_EDGES) {
            int s = src[e], d = dst[e];
            int b = d >> 8;
            bk[i] = (short)b;
            p[i] = (s << 8) | (d & 255);
            atomicAdd(&lh[b], 1);
        }
    }
    __syncthreads();
    // exclusive scan of lh[0..NB) by wave 0 (7 counters per lane)
    if (t < 64) {
        int c[7];
        int tot = 0;
#pragma unroll
        for (int j = 0; j < 7; j++) {
            int idx = t * 7 + j;
            c[j] = (idx < NB) ? lh[idx] : 0;
            tot += c[j];
        }
        int v = tot;
#pragma unroll
        for (int d = 1; d < 64; d <<= 1) {
            int u = __shfl_up(v, d);
            if (t >= d) v += u;
        }
        int run = v - tot;
#pragma unroll
        for (int j = 0; j < 7; j++) {
            int idx = t * 7 + j;
            if (idx < NB) lbase[idx] = run;
            run += c[j];
        }
        if (t == 63) lbase[NB] = run;  // total valid edges this block
    }
    __syncthreads();
    for (int i = t; i < NB; i += 512) lcur[i] = lbase[i];
    __syncthreads();
#pragma unroll
    for (int i = 0; i < 8; i++) {
        if (bk[i] >= 0) {
            int slot = atomicAdd(&lcur[bk[i]], 1);
            stage[slot] = p[i];
        }
    }
    __syncthreads();
    const int nval = lbase[NB];
    const int nv4 = nval >> 2;
    int4* o4 = (int4*)(part1 + e0);
    const int4* s4 = (const int4*)stage;
    for (int s = t; s < nv4; s += 512) o4[s] = s4[s];
    for (int s = (nv4 << 2) + t; s < nval; s += 512) part1[e0 + s] = stage[s];
    int* dblk = dir + blockIdx.x * (NB + 1);
    for (int i = t; i <= NB; i += 512) dblk[i] = lbase[i];
}

// One block per bucket (512 thr): gather this bucket's runs from all NPART
// block segments via dir, counting-sort by dst low byte in LDS, write sorted
// src to part2[bucket*BKT_CAP..] (fixed stride), emit nfo=(noff,cnt) and dinv.
__global__ __launch_bounds__(512) void k_sort(const int* __restrict__ part1,
                                              const int* __restrict__ dir,
                                              int* __restrict__ part2,
                                              int2* __restrict__ nfo,
                                              float* __restrict__ dinv) {
    __shared__ int sbeg[NPART], slen[NPART], spref[NPART];
    __shared__ int lcnt[256], lcur[256];
    __shared__ int wsum[4];
    __shared__ alignas(16) int stage[BKT_CAP];
    __shared__ alignas(16) int stage2[BKT_CAP];
    __shared__ int mtot;
    const int t = threadIdx.x, b = blockIdx.x;  // b = bucket
    for (int r = t; r < NPART; r += 512) {
        const int* dblk = dir + r * (NB + 1);
        int s0 = dblk[b];
        sbeg[r] = s0;
        slen[r] = dblk[b + 1] - s0;
    }
    if (t < 256) lcnt[t] = 0;
    __syncthreads();
    // exclusive scan of slen[0..NPART) by wave 0
    if (t < 64) {
        int c[7];
        int tot = 0;
#pragma unroll
        for (int j = 0; j < 7; j++) {
            int idx = t * 7 + j;
            c[j] = (idx < NPART) ? slen[idx] : 0;
            tot += c[j];
        }
        int v = tot;
#pragma unroll
        for (int d = 1; d < 64; d <<= 1) {
            int u = __shfl_up(v, d);
            if (t >= d) v += u;
        }
        int run = v - tot;
#pragma unroll
        for (int j = 0; j < 7; j++) {
            int idx = t * 7 + j;
            if (idx < NPART) spref[idx] = run;
            run += c[j];
        }
        if (t == 63) mtot = run;
    }
    __syncthreads();
    const int m = mtot;  // edges in this bucket
    // gather runs into contiguous LDS stage
    for (int r = t; r < NPART; r += 512) {
        const int* sp = part1 + r * EPB + sbeg[r];
        int o = spref[r], L = slen[r];
        for (int j = 0; j < L; j++) stage[o + j] = sp[j];
    }
    __syncthreads();
    // histogram by dst low byte
    for (int s = t; s < m; s += 512) atomicAdd(&lcnt[stage[s] & 255], 1);
    __syncthreads();
    // exclusive scan of 256 counters (waves 0-3)
    int c = 0, v = 0;
    const int lane = t & 63, w = t >> 6;
    if (t < 256) {
        c = lcnt[t];
        v = c;
#pragma unroll
        for (int d = 1; d < 64; d <<= 1) {
            int u = __shfl_up(v, d);
            if (lane >= d) v += u;
        }
        if (lane == 63) wsum[w] = v;
    }
    __syncthreads();
    if (t < 256) {
        int woff = 0;
#pragma unroll
        for (int k = 0; k < 4; k++) woff += (k < w) ? wsum[k] : 0;
        int excl = woff + v - c;
        lcur[t] = excl;
        int node = b * 256 + t;
        if (node < N_NODES) {
            nfo[node] = make_int2(b * BKT_CAP + excl, c);
            dinv[node] = rsqrtf((float)c + 1.0f);
        }
    }
    __syncthreads();
    for (int s = t; s < m; s += 512) {
        int pk = stage[s];
        int slot = atomicAdd(&lcur[pk & 255], 1);
        stage2[slot] = pk >> 8;  // unpack src
    }
    __syncthreads();
    int* outp = part2 + b * BKT_CAP;
    const int m4 = m >> 2;
    int4* o4 = (int4*)outp;
    const int4* s4 = (const int4*)stage2;
    for (int s = t; s < m4; s += 512) o4[s] = s4[s];
    for (int s = (m4 << 2) + t; s < m; s += 512) outp[s] = stage2[s];
}

// MFMA f16 GEMM: 64 rows x 64 cols per block (4 waves). x,w converted to fp16
// during LDS staging, stored in MFMA fragment order. fp32 accumulate; epilogue
// scales by dinv and stores hs16. Rows N_NODES..HS_ROWS-1 are written as zero
// (DUMMY row target for k_agg padding).
__global__ __launch_bounds__(256) void k_gemm(const float* __restrict__ x,
                                              const float* __restrict__ w,
                                              const float* __restrict__ dinv,
                                              __half* __restrict__ hs16) {
    __shared__ _Float16 afr[4][4][64][8];  // [row-tile][s][lane][j] 16 KB
    __shared__ _Float16 bfr[4][4][64][8];  // [col-tile][s][lane][j] 16 KB
    const int t = threadIdx.x;
    const int row0 = blockIdx.x * 64;

    // --- stage B: w[128][64] fp32 -> fp16 frag order ---
    {
        const int col = t & 63, s = t >> 6;
        const int c = col >> 4, lb = col & 15;
#pragma unroll
        for (int g = 0; g < 4; g++) {
            union { _Float16 h[8]; uint4 u; } pk;
#pragma unroll
            for (int j = 0; j < 8; j++)
                pk.h[j] = (_Float16)w[(s * 32 + g * 8 + j) * 64 + col];
            *(uint4*)&bfr[c][s][lb | (g << 4)][0] = pk.u;
        }
    }
    // --- stage A: x rows row0..row0+63 fp32 -> fp16 frag order, 8 floats/iter
    //     -> one full 16B uint4 LDS write (half the LDS writes of 4-float) ---
    {
        const float4* xg = (const float4*)(x + (size_t)row0 * D_IN);
#pragma unroll
        for (int i = 0; i < 4; i++) {
            int flat2 = t + i * 256;       // 8-float group index in [64][16]
            int row = flat2 >> 4;
            int k8 = (flat2 & 15) << 3;    // k base (multiple of 8)
            float4 va = make_float4(0.f, 0.f, 0.f, 0.f), vb = va;
            if (row0 + row < N_NODES) {
                va = xg[flat2 * 2];
                vb = xg[flat2 * 2 + 1];
            }
            union { _Float16 h[8]; uint4 u; } pk;
            pk.h[0] = (_Float16)va.x; pk.h[1] = (_Float16)va.y;
            pk.h[2] = (_Float16)va.z; pk.h[3] = (_Float16)va.w;
            pk.h[4] = (_Float16)vb.x; pk.h[5] = (_Float16)vb.y;
            pk.h[6] = (_Float16)vb.z; pk.h[7] = (_Float16)vb.w;
            *(uint4*)&afr[row >> 4][k8 >> 5][(row & 15) | (((k8 >> 3) & 3) << 4)][0] = pk.u;
        }
    }
    __syncthreads();

    const int wv = t >> 6, l = t & 63;
    f32x4 acc0 = {0.f, 0.f, 0.f, 0.f};
    f32x4 acc1 = {0.f, 0.f, 0.f, 0.f};
    f32x4 acc2 = {0.f, 0.f, 0.f, 0.f};
    f32x4 acc3 = {0.f, 0.f, 0.f, 0.f};
#pragma unroll
    for (int s = 0; s < 4; s++) {
        f16x8 a = *(const f16x8*)&afr[wv][s][l][0];
        f16x8 b0 = *(const f16x8*)&bfr[0][s][l][0];
        f16x8 b1 = *(const f16x8*)&bfr[1][s][l][0];
        f16x8 b2 = *(const f16x8*)&bfr[2][s][l][0];
        f16x8 b3 = *(const f16x8*)&bfr[3][s][l][0];
        acc0 = __builtin_amdgcn_mfma_f32_16x16x32_f16(a, b0, acc0, 0, 0, 0);
        acc1 = __builtin_amdgcn_mfma_f32_16x16x32_f16(a, b1, acc1, 0, 0, 0);
        acc2 = __builtin_amdgcn_mfma_f32_16x16x32_f16(a, b2, acc2, 0, 0, 0);
        acc3 = __builtin_amdgcn_mfma_f32_16x16x32_f16(a, b3, acc3, 0, 0, 0);
    }
    // epilogue: hs16[row][col] = fp16(acc * dinv[row]); rows >= N get dv=0 -> 0
    const int rbase = row0 + wv * 16 + ((l >> 4) << 2);
    const int cl = l & 15;
    _Float16* hsf = (_Float16*)hs16;
#pragma unroll
    for (int r = 0; r < 4; r++) {
        int row = rbase + r;  // < HS_ROWS by grid construction
        float dv = (row < N_NODES) ? dinv[row] : 0.f;
        size_t base = (size_t)row * 64 + cl;
        hsf[base +  0] = (_Float16)(acc0[r] * dv);
        hsf[base + 16] = (_Float16)(acc1[r] * dv);
        hsf[base + 32] = (_Float16)(acc2[r] * dv);
        hsf[base + 48] = (_Float16)(acc3[r] * dv);
    }
}

// One wave per node. 16-edge chunks: src indices s_loaded unconditionally into
// sixteen named scalars (no array -> no PromoteAlloca LDS demotion), padded to
// DUMMY (zero row) via uniform cselect. No tail code; all 8 gathers per lane
// issue back-to-back. Two 32-lane halves take even/odd edges; each lane covers
// 2 cols (__half2). fp32 accumulate, shfl_xor(32) reduce, fused epilogue.
__global__ __launch_bounds__(256) void k_agg(const int2* __restrict__ nfo,
                                             const int* __restrict__ ssrc,
                                             const float* __restrict__ dinv,
                                             const __half2* __restrict__ hs2,
                                             const float* __restrict__ bias,
                                             float* __restrict__ out) {
    int t = blockIdx.x * 256 + threadIdx.x;
    int node = t >> 6, lane = t & 63;
    if (node >= N_NODES) return;
    const int half = lane >> 5;   // which edge of each pair
    const int hl = lane & 31;     // half2 column index (cols 2*hl, 2*hl+1)
    int2 nc = nfo[node];
    const int beg = __builtin_amdgcn_readfirstlane(nc.x);
    const int cnt = __builtin_amdgcn_readfirstlane(nc.y);
    float ax0 = 0.f, ay0 = 0.f, ax1 = 0.f, ay1 = 0.f;
    float ax2 = 0.f, ay2 = 0.f, ax3 = 0.f, ay3 = 0.f;
    for (int k = 0; k < cnt; k += 16) {
        const int* p = ssrc + beg + k;
        int v0  = p[0],  v1  = p[1],  v2  = p[2],  v3  = p[3];
        int v4  = p[4],  v5  = p[5],  v6  = p[6],  v7  = p[7];
        int v8  = p[8],  v9  = p[9],  v10 = p[10], v11 = p[11];
        int v12 = p[12], v13 = p[13], v14 = p[14], v15 = p[15];
        int rem = cnt - k;  // uniform
        int s0  = (0  < rem) ? v0  : DUMMY;
        int s1  = (1  < rem) ? v1  : DUMMY;
        int s2  = (2  < rem) ? v2  : DUMMY;
        int s3  = (3  < rem) ? v3  : DUMMY;
        int s4  = (4  < rem) ? v4  : DUMMY;
        int s5  = (5  < rem) ? v5  : DUMMY;
        int s6  = (6  < rem) ? v6  : DUMMY;
        int s7  = (7  < rem) ? v7  : DUMMY;
        int s8  = (8  < rem) ? v8  : DUMMY;
        int s9  = (9  < rem) ? v9  : DUMMY;
        int s10 = (10 < rem) ? v10 : DUMMY;
        int s11 = (11 < rem) ? v11 : DUMMY;
        int s12 = (12 < rem) ? v12 : DUMMY;
        int s13 = (13 < rem) ? v13 : DUMMY;
        int s14 = (14 < rem) ? v14 : DUMMY;
        int s15 = (15 < rem) ? v15 : DUMMY;
        int r0 = half ? s1  : s0;
        int r1 = half ? s3  : s2;
        int r2 = half ? s5  : s4;
        int r3 = half ? s7  : s6;
        int r4 = half ? s9  : s8;
        int r5 = half ? s11 : s10;
        int r6 = half ? s13 : s12;
        int r7 = half ? s15 : s14;
        float2 f0 = __half22float2(hs2[((unsigned)r0 << 5) + hl]);
        float2 f1 = __half22float2(hs2[((unsigned)r1 << 5) + hl]);
        float2 f2 = __half22float2(hs2[((unsigned)r2 << 5) + hl]);
        float2 f3 = __half22float2(hs2[((unsigned)r3 << 5) + hl]);
        float2 f4 = __half22float2(hs2[((unsigned)r4 << 5) + hl]);
        float2 f5 = __half22float2(hs2[((unsigned)r5 << 5) + hl]);
        float2 f6 = __half22float2(hs2[((unsigned)r6 << 5) + hl]);
        float2 f7 = __half22float2(hs2[((unsigned)r7 << 5) + hl]);
        ax0 += f0.x; ay0 += f0.y;
        ax1 += f1.x; ay1 += f1.y;
        ax2 += f2.x; ay2 += f2.y;
        ax3 += f3.x; ay3 += f3.y;
        ax0 += f4.x; ay0 += f4.y;
        ax1 += f5.x; ay1 += f5.y;
        ax2 += f6.x; ay2 += f6.y;
        ax3 += f7.x; ay3 += f7.y;
    }
    float Ax = (ax0 + ax1) + (ax2 + ax3);
    float Ay = (ay0 + ay1) + (ay2 + ay3);
    Ax += __shfl_xor(Ax, 32);
    Ay += __shfl_xor(Ay, 32);
    float2 selfv = __half22float2(hs2[((unsigned)node << 5) + hl]);
    float dv = dinv[node];
    float2 bb = ((const float2*)bias)[hl];
    float vx = dv * (Ax + selfv.x) + bb.x;
    float vy = dv * (Ay + selfv.y) + bb.y;
    vx = vx > 0.f ? vx : 0.f;
    vy = vy > 0.f ? vy : 0.f;
    if (half == 0) {
        ((float2*)out)[((unsigned)node << 5) + hl] = make_float2(vx, vy);
    }
}

extern "C" void kernel_launch(void* const* d_in, const int* in_sizes, int n_in,
                              void* d_out, int out_size, void* d_ws, size_t ws_size,
                              hipStream_t stream) {
    const float* x    = (const float*)d_in[0];
    const int*   ei   = (const int*)d_in[1];   // [2][E] row-major
    const float* w    = (const float*)d_in[2];
    const float* bias = (const float*)d_in[3];
    float* out = (float*)d_out;

    float*  dinv  = (float*)d_ws;                        // N
    __half* hs16  = (__half*)(dinv + N_NODES);           // HS_ROWS*64 halves
    int*    part1 = (int*)(dinv + N_NODES) + HS_ROWS * 32;  // E
    int*    dir   = part1 + N_EDGES;                     // NPART*(NB+1)
    int*    part2 = dir + NPART * (NB + 1);              // NB*BKT_CAP+16
    int2*   nfo   = (int2*)(part2 + NB * BKT_CAP + 16);  // N int2

    const int* srcI = ei;
    const int* dstI = ei + N_EDGES;

    hipLaunchKernelGGL(k_part, dim3(NPART), dim3(512), 0, stream, srcI, dstI, part1, dir);
    hipLaunchKernelGGL(k_sort, dim3(NB), dim3(512), 0, stream, part1, dir, part2, nfo, dinv);
    hipLaunchKernelGGL(k_gemm, dim3((N_NODES + 63) / 64), dim3(256), 0, stream, x, w, dinv, hs16);
    hipLaunchKernelGGL(k_agg, dim3((N_NODES * 64) / 256), dim3(256), 0, stream,
                       nfo, part2, dinv, (const __half2*)hs16, bias, out);
}